// Round 17
// baseline (16805.240 us; speedup 1.0000x reference)
//
#include <hip/hip_runtime.h>
#include <hip/hip_bf16.h>

// LSTM classifier: emb gather -> input GEMM (fp16 MFMA) -> persistent
// recurrence with DATA-CARRIED sync (poison-tagged h words) -> logits.
// R17 = R16 + SENTINEL POLL: during the wait, each thread spins on one 16B
// granule (s_sleep(2) backoff) instead of sweeping its full 128B slice;
// the full R16 sweep+check runs only after the sentinel clears. Cuts the
// chip-wide LLC poll traffic 8x (the poll storm queues ahead of the very
// h stores being awaited) and tightens detection granularity ~3x.
//
// Workspace layout (bytes):
//   emb16   @ 0          : 50257*1024*2 = 102,926,336
//   wih16   @ 102926336  : 4096*1024*2  =   8,388,608
//   wr16    @ 111314944  : 4096*1024*2  =   8,388,608   (W_hh reordered, fp16)
//   bias    @ 119703552  : 4096*4       =      16,384   (b_ih + b_hh, f32)
//   xg      @ 119719936  : 65536*4096*2 = 536,870,912   (x_gates fp16, [t][b][R'])
//   h_all   @ 656590848  : 2049*32*1024*2 = 134,283,264 (h; t>=1 poisoned 0xFFFF per launch)
//   total: 790,874,112

typedef _Float16 f16;
typedef _Float16 f16x8 __attribute__((ext_vector_type(8)));
typedef _Float16 f16x4 __attribute__((ext_vector_type(4)));
typedef float    f32x4 __attribute__((ext_vector_type(4)));
typedef unsigned long long u64;

#define B_    32
#define T_    2048
#define H_    1024
#define G4_   4096

__device__ __forceinline__ void gl_lds16(const void* g, void* l) {
  __builtin_amdgcn_global_load_lds(
      (const __attribute__((address_space(1))) void*)g,
      (__attribute__((address_space(3))) void*)l, 16, 0, 0);
}

// agent-scope (LLC) 2B store — write-through past the non-coherent XCD L2s
__device__ __forceinline__ void llc_st16(void* p, unsigned short v) {
  __hip_atomic_store((unsigned short*)p, v, __ATOMIC_RELAXED, __HIP_MEMORY_SCOPE_AGENT);
}

// fast activations: v_exp_f32 + v_rcp_f32 (no libm branches on critical path)
__device__ __forceinline__ float fast_sigmoid(float v) {
  return __builtin_amdgcn_rcpf(1.f + __expf(-v));
}
__device__ __forceinline__ float fast_tanh(float v) {
  return 1.f - 2.f * __builtin_amdgcn_rcpf(1.f + __expf(2.f * v));
}

// ---------------- conversions ----------------

__global__ void k_cvt_f16(const float* __restrict__ in, f16* __restrict__ out, long n4) {
  long i = (long)blockIdx.x * blockDim.x + threadIdx.x;
  if (i >= n4) return;
  float4 v = ((const float4*)in)[i];
  f16x4 o; o[0] = (f16)v.x; o[1] = (f16)v.y; o[2] = (f16)v.z; o[3] = (f16)v.w;
  *(f16x4*)(out + i * 4) = o;
}

// W_hh row (q*1024 + j) -> wr16 row R' = (j>>4)*64 + (j&15)*4 + q; fp16.
// => WG wid owns contiguous rows [wid*64, wid*64+64) = h-dims [wid*16, +16).
__global__ void k_whh_reorder(const float* __restrict__ whh, f16* __restrict__ wr) {
  unsigned i = blockIdx.x * blockDim.x + threadIdx.x;   // one thread per 8 elems
  unsigned e0 = i * 8;
  unsigned R = e0 >> 10, k = e0 & 1023;
  unsigned q = R >> 10, j = R & 1023;
  unsigned outR = ((j >> 4) << 6) + ((j & 15) << 2) + q;
  float4 v0 = ((const float4*)whh)[e0 / 4];
  float4 v1 = ((const float4*)whh)[e0 / 4 + 1];
  f16x8 o;
  o[0] = (f16)v0.x; o[1] = (f16)v0.y; o[2] = (f16)v0.z; o[3] = (f16)v0.w;
  o[4] = (f16)v1.x; o[5] = (f16)v1.y; o[6] = (f16)v1.z; o[7] = (f16)v1.w;
  *(f16x8*)&wr[((size_t)outR << 10) + k] = o;
}

__global__ void k_bias(const float* __restrict__ bi, const float* __restrict__ bh,
                       float* __restrict__ bo) {
  unsigned i = blockIdx.x * blockDim.x + threadIdx.x;
  if (i < G4_) bo[i] = bi[i] + bh[i];
}

// ---------------- input GEMM: xg[m][R'(n)] = emb[seq] @ W_ih^T + bias ----------------
// m = t*32 + b (so xg layout is [t][b][R']); 128x128 tile, BK=64, 4 waves.

__global__ __launch_bounds__(256) void k_gemm_xg(
    const int* __restrict__ seq, const f16* __restrict__ emb16,
    const f16* __restrict__ wih16, const float* __restrict__ bias,
    f16* __restrict__ xg) {
  __shared__ f16 As[128 * 64];
  __shared__ f16 Bs[128 * 64];
  const unsigned tid = threadIdx.x;
  const unsigned w = tid >> 6, lane = tid & 63;
  const unsigned bid = blockIdx.x;
  const unsigned tn = bid & 31, tm = bid >> 5;
  const unsigned wm = (w >> 1) * 64, wn = (w & 1) * 64;

  f32x4 zero = {0.f, 0.f, 0.f, 0.f};
  f32x4 acc[4][4];
#pragma unroll
  for (int i = 0; i < 4; ++i)
#pragma unroll
    for (int j = 0; j < 4; ++j) acc[i][j] = zero;

  for (unsigned kk = 0; kk < 16; ++kk) {
    const unsigned k0 = kk * 64;
#pragma unroll
    for (unsigned c = 0; c < 4; ++c) {
      unsigned idx = c * 256 + tid;
      unsigned row = idx >> 3, ch = idx & 7;
      unsigned chs = ch ^ (row & 7);
      unsigned m = tm * 128 + row;
      unsigned t = m >> 5, b = m & 31;
      int e = seq[b * 2048 + t];
      const f16* src = emb16 + ((size_t)e << 10) + k0 + chs * 8;
      gl_lds16(src, (char*)As + c * 4096 + w * 1024);
    }
#pragma unroll
    for (unsigned c = 0; c < 4; ++c) {
      unsigned idx = c * 256 + tid;
      unsigned row = idx >> 3, ch = idx & 7;
      unsigned chs = ch ^ (row & 7);
      unsigned n = tn * 128 + row;
      const f16* src = wih16 + ((size_t)n << 10) + k0 + chs * 8;
      gl_lds16(src, (char*)Bs + c * 4096 + w * 1024);
    }
    __syncthreads();
#pragma unroll
    for (unsigned ks = 0; ks < 2; ++ks) {
      f16x8 af[4], bf[4];
      unsigned kc = ks * 4 + (lane >> 4);
#pragma unroll
      for (unsigned fm = 0; fm < 4; ++fm) {
        unsigned r = wm + fm * 16 + (lane & 15);
        af[fm] = *(const f16x8*)&As[r * 64 + ((kc ^ (r & 7)) << 3)];
      }
#pragma unroll
      for (unsigned fn = 0; fn < 4; ++fn) {
        unsigned r = wn + fn * 16 + (lane & 15);
        bf[fn] = *(const f16x8*)&Bs[r * 64 + ((kc ^ (r & 7)) << 3)];
      }
#pragma unroll
      for (unsigned fm = 0; fm < 4; ++fm)
#pragma unroll
        for (unsigned fn = 0; fn < 4; ++fn)
          acc[fm][fn] = __builtin_amdgcn_mfma_f32_16x16x32_f16(af[fm], bf[fn], acc[fm][fn], 0, 0, 0);
    }
    __syncthreads();
  }
  // epilogue: + bias, fp16 store into gate-interleaved layout R'
#pragma unroll
  for (unsigned fn = 0; fn < 4; ++fn) {
    unsigned n = tn * 128 + wn + fn * 16 + (lane & 15);
    unsigned q = n >> 10, j = n & 1023;
    unsigned Rp = ((j >> 4) << 6) + ((j & 15) << 2) + q;
    float bv = bias[n];
#pragma unroll
    for (unsigned fm = 0; fm < 4; ++fm) {
#pragma unroll
      for (unsigned rg = 0; rg < 4; ++rg) {
        unsigned m = tm * 128 + wm + fm * 16 + (lane >> 4) * 4 + rg;
        xg[(size_t)m * G4_ + Rp] = (f16)(acc[fm][fn][rg] + bv);
      }
    }
  }
}

// ---------------- persistent LSTM recurrence, 2-phase, operand-swapped ----------------
// 64 WGs x 256 threads (4 waves = 4 M-tiles of 16 W rows, FULL K per wave:
// k<512 from Wl, k>=512 from per-wave breg). WG wid owns h-dims [wid*16,+16).
// Per step t, two phases (s=0: batches 0..15, s=1: 16..31):
//   [sentinel poll 16B][full sweep per-u16 poison][stage -> Hl[phase&1]][bar]
//   [32-MFMA swapped][act (no shuffles) + llc_st16].
// Swapped mfma(W_frag, h_frag, acc): lane (rl=batch, hi=dim-within-4) holds
// acc[z] = gate z of dim wid*16+nt*4+hi — zero-shuffle gate combine.

__global__ __launch_bounds__(256) void k_lstm(
    const f16* __restrict__ xg, const f16* __restrict__ wr16,
    f16* __restrict__ h_all) {
  __shared__ f16 Wl[64 * 512];       // 64 KB: W_hh slice, k < 512
  __shared__ f16 Hl[2][16 * 1024];   // 64 KB: h staging, double-buffered by phase
  const unsigned tid = threadIdx.x;
  const unsigned nt = tid >> 6, lane = tid & 63;   // 4 waves = 4 M-tiles
  const unsigned wid = blockIdx.x;                 // 0..63
  const unsigned rl = lane & 15, hi = lane >> 4;

  // stage W k<512 (64 rows x 64 16B-chunks), source-swizzled, linear LDS dest
  for (unsigned c = 0; c < 16; ++c) {
    unsigned idx = c * 256 + tid;
    unsigned row = idx >> 6, ch = idx & 63;
    unsigned chs = ch ^ (row & 7);
    const f16* src = wr16 + (((size_t)wid * 64 + row) << 10) + chs * 8;
    gl_lds16(src, (char*)Wl + c * 4096 + nt * 1024);
  }

  const unsigned rWl = nt * 16 + rl;          // W row 0..63 within slice
  const unsigned dd = wid * 16 + nt * 4 + hi; // this lane's h-dim

  // breg: k in [512,1024) for this wave's own rows (asm-pinned; R3 lesson)
  f16x8 breg[16];
  {
    const f16* wp = wr16 + (((size_t)wid * 64 + rWl) << 10) + 512 + hi * 8;
#pragma unroll
    for (int j = 0; j < 16; ++j) {
      asm volatile("global_load_dwordx4 %0, %1, off\n\ts_waitcnt vmcnt(0)"
                   : "=v"(breg[j]) : "v"(wp + j * 32) : "memory");
    }
  }
  __syncthreads();   // Wl staged (barrier drains lgkm/vm) + breg loaded

  // staging: 16 rows x 128 chunks(16B); thread owns row tid>>4, 8 chunks
  const unsigned srow = tid >> 4;            // 0..15 (batch within stream)
  const unsigned scg = (tid & 15) * 8;       // first chunk index
  float cA = 0.f, cB = 0.f;

  for (unsigned t = 1; t <= (unsigned)T_; ++t) {
#pragma unroll
    for (int s = 0; s < 2; ++s) {
      const unsigned sb16 = s * 16;
      const unsigned pb = ((t - 1) * 2 + s) & 1;   // Hl phase buffer
      // xv: the 4 gate pre-activations for (dd, batch sb16+rl) — contiguous
      f16x4 xv4 = *(const f16x4*)(xg + ((size_t)(t - 1) * B_ + sb16 + rl) * G4_
                                  + wid * 64 + (nt * 4 + hi) * 4);
      const f16* gp = h_all + ((size_t)(t - 1) * B_ + sb16 + srow) * H_ + scg * 8;
      // ---- sentinel poll: 16B granule 0 only (8x less LLC poll traffic) ----
      {
        f16x8 sv;
        while (true) {
          asm volatile("global_load_dwordx4 %0, %1, off sc0 sc1\n\t"
                       "s_waitcnt vmcnt(0)"
                       : "=v"(sv) : "v"(gp) : "memory");
          __builtin_amdgcn_sched_barrier(0);   // rule #18
          union { f16x8 v; unsigned u[4]; } uu; uu.v = sv;
          bool ok = true;
#pragma unroll
          for (int k2 = 0; k2 < 4; ++k2) {
            unsigned wv = uu.u[k2];
            ok = ok && ((wv & 0xFFFFu) != 0xFFFFu) && ((wv >> 16) != 0xFFFFu);
          }
          if (ok) break;
          __builtin_amdgcn_s_sleep(2);
        }
      }
      // ---- full sweep (R16-identical): per-u16 poison check, retry on fail ----
      f16x8 st[8];
      while (true) {
#pragma unroll
        for (int j = 0; j < 8; ++j)
          asm volatile("global_load_dwordx4 %0, %1, off sc0 sc1"
                       : "=v"(st[j]) : "v"(gp + j * 8));
        asm volatile("s_waitcnt vmcnt(0)" ::: "memory");
        __builtin_amdgcn_sched_barrier(0);   // rule #18
        bool ok = true;
#pragma unroll
        for (int j = 0; j < 8; ++j) {
          union { f16x8 v; unsigned u[4]; } uu; uu.v = st[j];
#pragma unroll
          for (int k2 = 0; k2 < 4; ++k2) {
            unsigned wv = uu.u[k2];
            ok = ok && ((wv & 0xFFFFu) != 0xFFFFu) && ((wv >> 16) != 0xFFFFu);
          }
        }
        if (ok) break;
        __builtin_amdgcn_s_sleep(1);
      }
      // ---- stage into dual-XOR swizzled Hl[pb] ----
#pragma unroll
      for (int j = 0; j < 8; ++j) {
        unsigned cc = scg + j;
        unsigned pos = cc ^ (srow & 7) ^ ((cc >> 3) & 7);   // dual-XOR swizzle
        *(f16x8*)&Hl[pb][srow * 1024 + (pos << 3)] = st[j];
      }
      __syncthreads();   // h-tile staged (drains lgkm: st[] safe to reuse)

      // ---- gates^T = W rows @ h^T : swapped operands, full K per wave ----
      f32x4 acc0 = {0.f, 0.f, 0.f, 0.f};
      f32x4 acc1 = {0.f, 0.f, 0.f, 0.f};
#pragma unroll
      for (unsigned ks = 0; ks < 16; ks += 2) {
        unsigned c0 = ks * 4 + hi, c1 = c0 + 4;
        unsigned p0 = c0 ^ (rl & 7) ^ ((c0 >> 3) & 7);
        unsigned p1 = c1 ^ (rl & 7) ^ ((c1 >> 3) & 7);
        f16x8 h0 = *(const f16x8*)&Hl[pb][rl * 1024 + (p0 << 3)];
        f16x8 h1 = *(const f16x8*)&Hl[pb][rl * 1024 + (p1 << 3)];
        f16x8 w0 = *(const f16x8*)&Wl[rWl * 512 + ((c0 ^ (rWl & 7)) << 3)];
        f16x8 w1 = *(const f16x8*)&Wl[rWl * 512 + ((c1 ^ (rWl & 7)) << 3)];
        acc0 = __builtin_amdgcn_mfma_f32_16x16x32_f16(w0, h0, acc0, 0, 0, 0);
        acc1 = __builtin_amdgcn_mfma_f32_16x16x32_f16(w1, h1, acc1, 0, 0, 0);
      }
#pragma unroll
      for (unsigned ks = 16; ks < 32; ks += 2) {
        unsigned c0 = ks * 4 + hi, c1 = c0 + 4;
        unsigned p0 = c0 ^ (rl & 7) ^ ((c0 >> 3) & 7);
        unsigned p1 = c1 ^ (rl & 7) ^ ((c1 >> 3) & 7);
        f16x8 h0 = *(const f16x8*)&Hl[pb][rl * 1024 + (p0 << 3)];
        f16x8 h1 = *(const f16x8*)&Hl[pb][rl * 1024 + (p1 << 3)];
        acc0 = __builtin_amdgcn_mfma_f32_16x16x32_f16(breg[ks - 16], h0, acc0, 0, 0, 0);
        acc1 = __builtin_amdgcn_mfma_f32_16x16x32_f16(breg[ks - 15], h1, acc1, 0, 0, 0);
      }
      // ---- activations: lane-local i,f,g,o (NO shuffles) + 2B h store ----
      {
        float gi = acc0[0] + acc1[0] + (float)xv4[0];
        float gf = acc0[1] + acc1[1] + (float)xv4[1];
        float gg = acc0[2] + acc1[2] + (float)xv4[2];
        float go = acc0[3] + acc1[3] + (float)xv4[3];
        float i_ = fast_sigmoid(gi);
        float f_ = fast_sigmoid(gf);
        float g_ = fast_tanh(gg);
        float o_ = fast_sigmoid(go);
        float c_ = (s == 0) ? cA : cB;       // s compile-time (unrolled)
        c_ = f_ * c_ + i_ * g_;
        if (s == 0) cA = c_; else cB = c_;
        float hv = o_ * fast_tanh(c_);
        f16 hv16 = (f16)hv;
        llc_st16(h_all + ((size_t)t * B_ + sb16 + rl) * H_ + dd,
                 __builtin_bit_cast(unsigned short, hv16));
      }
      // store drains under the next phase's spin vmcnt(0); Hl double-buffer
      // makes a second barrier unnecessary (next staging hits the other buf).
    }
  }
}

// ---------------- logits: out[b][t][c] = relu(h[t+1]) . W_score[c] ----------------

__global__ __launch_bounds__(256) void k_logits(
    const f16* __restrict__ h_all, const float* __restrict__ wsc,
    float* __restrict__ out) {
  __shared__ float Ws[2048];
  unsigned tid = threadIdx.x;
  for (unsigned i = tid; i < 512; i += 256) ((float4*)Ws)[i] = ((const float4*)wsc)[i];
  __syncthreads();
  unsigned w = tid >> 6, lane = tid & 63;
  unsigned base = blockIdx.x * 64 + w * 16;
  for (unsigned i = 0; i < 16; ++i) {
    unsigned idx = base + i;                // 0..65535
    unsigned tt = idx >> 5, b = idx & 31;
    const f16* hp = h_all + ((size_t)(idx + 32)) * H_ + lane * 16;
    f16x8 ha = *(const f16x8*)hp;
    f16x8 hb = *(const f16x8*)(hp + 8);
    float s0 = 0.f, s1 = 0.f;
#pragma unroll
    for (int z = 0; z < 8; ++z) {
      float hv = fmaxf((float)ha[z], 0.f);
      s0 += hv * Ws[lane * 16 + z];
      s1 += hv * Ws[1024 + lane * 16 + z];
    }
#pragma unroll
    for (int z = 0; z < 8; ++z) {
      float hv = fmaxf((float)hb[z], 0.f);
      s0 += hv * Ws[lane * 16 + 8 + z];
      s1 += hv * Ws[1024 + lane * 16 + 8 + z];
    }
#pragma unroll
    for (int off = 32; off; off >>= 1) {
      s0 += __shfl_xor(s0, off, 64);
      s1 += __shfl_xor(s1, off, 64);
    }
    if (lane == 0) {
      out[((size_t)b * T_ + tt) * 2 + 0] = s0;
      out[((size_t)b * T_ + tt) * 2 + 1] = s1;
    }
  }
}

// ---------------- launch ----------------

extern "C" void kernel_launch(void* const* d_in, const int* in_sizes, int n_in,
                              void* d_out, int out_size, void* d_ws, size_t ws_size,
                              hipStream_t stream) {
  const int*   seq = (const int*)d_in[0];
  const float* emb = (const float*)d_in[1];
  const float* wih = (const float*)d_in[2];
  const float* whh = (const float*)d_in[3];
  const float* bih = (const float*)d_in[4];
  const float* bhh = (const float*)d_in[5];
  const float* wsc = (const float*)d_in[6];
  float* out = (float*)d_out;
  char* ws = (char*)d_ws;

  const size_t NEED = 790874112ull;
  if (ws_size < NEED) return;  // workspace too small: output stays zero (detectable)

  f16*   emb16 = (f16*)(ws);
  f16*   wih16 = (f16*)(ws + 102926336ull);
  f16*   wr16  = (f16*)(ws + 111314944ull);
  float* bias  = (float*)(ws + 119703552ull);
  f16*   xg    = (f16*)(ws + 119719936ull);
  f16*   h_all = (f16*)(ws + 656590848ull);

  hipMemsetAsync(h_all, 0, (size_t)B_ * H_ * 2, stream);                // h_0 = 0
  hipMemsetAsync((char*)h_all + (size_t)B_ * H_ * 2, 0xFF,
                 (size_t)T_ * B_ * H_ * 2, stream);                     // poison h_1..h_T

  k_cvt_f16<<<50257, 256, 0, stream>>>(emb, emb16, 12865792L);
  k_cvt_f16<<<4096, 256, 0, stream>>>(wih, wih16, 1048576L);
  k_whh_reorder<<<2048, 256, 0, stream>>>(whh, wr16);
  k_bias<<<16, 256, 0, stream>>>(bih, bhh, bias);

  k_gemm_xg<<<16384, 256, 0, stream>>>(seq, emb16, wih16, bias, xg);
  k_lstm<<<64, 256, 0, stream>>>(xg, wr16, h_all);
  k_logits<<<1024, 256, 0, stream>>>(h_all, wsc, out);
}

// Round 18
// 12777.541 us; speedup vs baseline: 1.3152x; 1.3152x over previous
//
#include <hip/hip_runtime.h>
#include <hip/hip_bf16.h>

// LSTM classifier: emb gather -> input GEMM (fp16 MFMA) -> persistent
// recurrence with DATA-CARRIED sync (poison-tagged h words) -> logits.
// R18 = R16 (best: 14.49ms) + 8B-PACKED h stores: lanes hi=1..3 shuffle
// their h value to hi=0, which stores f16x4 (4 contiguous dims) with one
// atomic llc_st64. Store count 4x down; each consumer 16B granule now
// assembles from 2 atomic 8B stores (was 8x 2B) -> tighter arrival spread,
// no sub-8B partial-write merging. Poison check back to per-u64 (each 8B
// half-granule is atomic: either all-poison or all-real).
//
// Workspace layout (bytes):
//   emb16   @ 0          : 50257*1024*2 = 102,926,336
//   wih16   @ 102926336  : 4096*1024*2  =   8,388,608
//   wr16    @ 111314944  : 4096*1024*2  =   8,388,608   (W_hh reordered, fp16)
//   bias    @ 119703552  : 4096*4       =      16,384   (b_ih + b_hh, f32)
//   xg      @ 119719936  : 65536*4096*2 = 536,870,912   (x_gates fp16, [t][b][R'])
//   h_all   @ 656590848  : 2049*32*1024*2 = 134,283,264 (h; t>=1 poisoned 0xFFFF per launch)
//   total: 790,874,112

typedef _Float16 f16;
typedef _Float16 f16x8 __attribute__((ext_vector_type(8)));
typedef _Float16 f16x4 __attribute__((ext_vector_type(4)));
typedef float    f32x4 __attribute__((ext_vector_type(4)));
typedef unsigned long long u64;

#define B_    32
#define T_    2048
#define H_    1024
#define G4_   4096

__device__ __forceinline__ void gl_lds16(const void* g, void* l) {
  __builtin_amdgcn_global_load_lds(
      (const __attribute__((address_space(1))) void*)g,
      (__attribute__((address_space(3))) void*)l, 16, 0, 0);
}

// agent-scope (LLC) 8B store — write-through past the non-coherent XCD L2s
__device__ __forceinline__ void llc_st64(void* p, u64 v) {
  __hip_atomic_store((u64*)p, v, __ATOMIC_RELAXED, __HIP_MEMORY_SCOPE_AGENT);
}

// fast activations: v_exp_f32 + v_rcp_f32 (no libm branches on critical path)
__device__ __forceinline__ float fast_sigmoid(float v) {
  return __builtin_amdgcn_rcpf(1.f + __expf(-v));
}
__device__ __forceinline__ float fast_tanh(float v) {
  return 1.f - 2.f * __builtin_amdgcn_rcpf(1.f + __expf(2.f * v));
}

// ---------------- conversions ----------------

__global__ void k_cvt_f16(const float* __restrict__ in, f16* __restrict__ out, long n4) {
  long i = (long)blockIdx.x * blockDim.x + threadIdx.x;
  if (i >= n4) return;
  float4 v = ((const float4*)in)[i];
  f16x4 o; o[0] = (f16)v.x; o[1] = (f16)v.y; o[2] = (f16)v.z; o[3] = (f16)v.w;
  *(f16x4*)(out + i * 4) = o;
}

// W_hh row (q*1024 + j) -> wr16 row R' = (j>>4)*64 + (j&15)*4 + q; fp16.
// => WG wid owns contiguous rows [wid*64, wid*64+64) = h-dims [wid*16, +16).
__global__ void k_whh_reorder(const float* __restrict__ whh, f16* __restrict__ wr) {
  unsigned i = blockIdx.x * blockDim.x + threadIdx.x;   // one thread per 8 elems
  unsigned e0 = i * 8;
  unsigned R = e0 >> 10, k = e0 & 1023;
  unsigned q = R >> 10, j = R & 1023;
  unsigned outR = ((j >> 4) << 6) + ((j & 15) << 2) + q;
  float4 v0 = ((const float4*)whh)[e0 / 4];
  float4 v1 = ((const float4*)whh)[e0 / 4 + 1];
  f16x8 o;
  o[0] = (f16)v0.x; o[1] = (f16)v0.y; o[2] = (f16)v0.z; o[3] = (f16)v0.w;
  o[4] = (f16)v1.x; o[5] = (f16)v1.y; o[6] = (f16)v1.z; o[7] = (f16)v1.w;
  *(f16x8*)&wr[((size_t)outR << 10) + k] = o;
}

__global__ void k_bias(const float* __restrict__ bi, const float* __restrict__ bh,
                       float* __restrict__ bo) {
  unsigned i = blockIdx.x * blockDim.x + threadIdx.x;
  if (i < G4_) bo[i] = bi[i] + bh[i];
}

// ---------------- input GEMM: xg[m][R'(n)] = emb[seq] @ W_ih^T + bias ----------------
// m = t*32 + b (so xg layout is [t][b][R']); 128x128 tile, BK=64, 4 waves.

__global__ __launch_bounds__(256) void k_gemm_xg(
    const int* __restrict__ seq, const f16* __restrict__ emb16,
    const f16* __restrict__ wih16, const float* __restrict__ bias,
    f16* __restrict__ xg) {
  __shared__ f16 As[128 * 64];
  __shared__ f16 Bs[128 * 64];
  const unsigned tid = threadIdx.x;
  const unsigned w = tid >> 6, lane = tid & 63;
  const unsigned bid = blockIdx.x;
  const unsigned tn = bid & 31, tm = bid >> 5;
  const unsigned wm = (w >> 1) * 64, wn = (w & 1) * 64;

  f32x4 zero = {0.f, 0.f, 0.f, 0.f};
  f32x4 acc[4][4];
#pragma unroll
  for (int i = 0; i < 4; ++i)
#pragma unroll
    for (int j = 0; j < 4; ++j) acc[i][j] = zero;

  for (unsigned kk = 0; kk < 16; ++kk) {
    const unsigned k0 = kk * 64;
#pragma unroll
    for (unsigned c = 0; c < 4; ++c) {
      unsigned idx = c * 256 + tid;
      unsigned row = idx >> 3, ch = idx & 7;
      unsigned chs = ch ^ (row & 7);
      unsigned m = tm * 128 + row;
      unsigned t = m >> 5, b = m & 31;
      int e = seq[b * 2048 + t];
      const f16* src = emb16 + ((size_t)e << 10) + k0 + chs * 8;
      gl_lds16(src, (char*)As + c * 4096 + w * 1024);
    }
#pragma unroll
    for (unsigned c = 0; c < 4; ++c) {
      unsigned idx = c * 256 + tid;
      unsigned row = idx >> 3, ch = idx & 7;
      unsigned chs = ch ^ (row & 7);
      unsigned n = tn * 128 + row;
      const f16* src = wih16 + ((size_t)n << 10) + k0 + chs * 8;
      gl_lds16(src, (char*)Bs + c * 4096 + w * 1024);
    }
    __syncthreads();
#pragma unroll
    for (unsigned ks = 0; ks < 2; ++ks) {
      f16x8 af[4], bf[4];
      unsigned kc = ks * 4 + (lane >> 4);
#pragma unroll
      for (unsigned fm = 0; fm < 4; ++fm) {
        unsigned r = wm + fm * 16 + (lane & 15);
        af[fm] = *(const f16x8*)&As[r * 64 + ((kc ^ (r & 7)) << 3)];
      }
#pragma unroll
      for (unsigned fn = 0; fn < 4; ++fn) {
        unsigned r = wn + fn * 16 + (lane & 15);
        bf[fn] = *(const f16x8*)&Bs[r * 64 + ((kc ^ (r & 7)) << 3)];
      }
#pragma unroll
      for (unsigned fm = 0; fm < 4; ++fm)
#pragma unroll
        for (unsigned fn = 0; fn < 4; ++fn)
          acc[fm][fn] = __builtin_amdgcn_mfma_f32_16x16x32_f16(af[fm], bf[fn], acc[fm][fn], 0, 0, 0);
    }
    __syncthreads();
  }
  // epilogue: + bias, fp16 store into gate-interleaved layout R'
#pragma unroll
  for (unsigned fn = 0; fn < 4; ++fn) {
    unsigned n = tn * 128 + wn + fn * 16 + (lane & 15);
    unsigned q = n >> 10, j = n & 1023;
    unsigned Rp = ((j >> 4) << 6) + ((j & 15) << 2) + q;
    float bv = bias[n];
#pragma unroll
    for (unsigned fm = 0; fm < 4; ++fm) {
#pragma unroll
      for (unsigned rg = 0; rg < 4; ++rg) {
        unsigned m = tm * 128 + wm + fm * 16 + (lane >> 4) * 4 + rg;
        xg[(size_t)m * G4_ + Rp] = (f16)(acc[fm][fn][rg] + bv);
      }
    }
  }
}

// ---------------- persistent LSTM recurrence, 2-phase, operand-swapped ----------------
// 64 WGs x 256 threads (4 waves = 4 M-tiles of 16 W rows, FULL K per wave:
// k<512 from Wl, k>=512 from per-wave breg). WG wid owns h-dims [wid*16,+16).
// Per step t, two phases (s=0: batches 0..15, s=1: 16..31):
//   [spin per-u64 poison][stage -> Hl[phase&1]][bar][32-MFMA swapped]
//   [act (lane-local i,f,g,o) -> 3-shuffle pack -> ONE 8B llc_st64 per batch].
// Swapped mfma(W_frag, h_frag, acc): lane (rl=batch, hi=dim-within-4) holds
// acc[z] = gate z of dim wid*16+nt*4+hi — zero-shuffle gate combine.

__global__ __launch_bounds__(256) void k_lstm(
    const f16* __restrict__ xg, const f16* __restrict__ wr16,
    f16* __restrict__ h_all) {
  __shared__ f16 Wl[64 * 512];       // 64 KB: W_hh slice, k < 512
  __shared__ f16 Hl[2][16 * 1024];   // 64 KB: h staging, double-buffered by phase
  const unsigned tid = threadIdx.x;
  const unsigned nt = tid >> 6, lane = tid & 63;   // 4 waves = 4 M-tiles
  const unsigned wid = blockIdx.x;                 // 0..63
  const unsigned rl = lane & 15, hi = lane >> 4;

  // stage W k<512 (64 rows x 64 16B-chunks), source-swizzled, linear LDS dest
  for (unsigned c = 0; c < 16; ++c) {
    unsigned idx = c * 256 + tid;
    unsigned row = idx >> 6, ch = idx & 63;
    unsigned chs = ch ^ (row & 7);
    const f16* src = wr16 + (((size_t)wid * 64 + row) << 10) + chs * 8;
    gl_lds16(src, (char*)Wl + c * 4096 + nt * 1024);
  }

  const unsigned rWl = nt * 16 + rl;          // W row 0..63 within slice
  // breg: k in [512,1024) for this wave's own rows (asm-pinned; R3 lesson)
  f16x8 breg[16];
  {
    const f16* wp = wr16 + (((size_t)wid * 64 + rWl) << 10) + 512 + hi * 8;
#pragma unroll
    for (int j = 0; j < 16; ++j) {
      asm volatile("global_load_dwordx4 %0, %1, off\n\ts_waitcnt vmcnt(0)"
                   : "=v"(breg[j]) : "v"(wp + j * 32) : "memory");
    }
  }
  __syncthreads();   // Wl staged (barrier drains lgkm/vm) + breg loaded

  // staging: 16 rows x 128 chunks(16B); thread owns row tid>>4, 8 chunks
  const unsigned srow = tid >> 4;            // 0..15 (batch within stream)
  const unsigned scg = (tid & 15) * 8;       // first chunk index
  float cA = 0.f, cB = 0.f;

  for (unsigned t = 1; t <= (unsigned)T_; ++t) {
#pragma unroll
    for (int s = 0; s < 2; ++s) {
      const unsigned sb16 = s * 16;
      const unsigned pb = ((t - 1) * 2 + s) & 1;   // Hl phase buffer
      // xv: the 4 gate pre-activations for (dim, batch sb16+rl) — contiguous
      f16x4 xv4 = *(const f16x4*)(xg + ((size_t)(t - 1) * B_ + sb16 + rl) * G4_
                                  + wid * 64 + (nt * 4 + hi) * 4);
      const f16* gp = h_all + ((size_t)(t - 1) * B_ + sb16 + srow) * H_ + scg * 8;
      // ---- spin: full sweep, per-u64 poison check (8B halves are atomic) ----
      f16x8 st[8];
      while (true) {
#pragma unroll
        for (int j = 0; j < 8; ++j)
          asm volatile("global_load_dwordx4 %0, %1, off sc0 sc1"
                       : "=v"(st[j]) : "v"(gp + j * 8));
        asm volatile("s_waitcnt vmcnt(0)" ::: "memory");
        __builtin_amdgcn_sched_barrier(0);   // rule #18
        bool ok = true;
#pragma unroll
        for (int j = 0; j < 8; ++j) {
          union { f16x8 v; u64 u[2]; } uu; uu.v = st[j];
          ok = ok && (uu.u[0] != ~0ull) && (uu.u[1] != ~0ull);
        }
        if (ok) break;
        __builtin_amdgcn_s_sleep(1);
      }
      // ---- stage into dual-XOR swizzled Hl[pb] ----
#pragma unroll
      for (int j = 0; j < 8; ++j) {
        unsigned cc = scg + j;
        unsigned pos = cc ^ (srow & 7) ^ ((cc >> 3) & 7);   // dual-XOR swizzle
        *(f16x8*)&Hl[pb][srow * 1024 + (pos << 3)] = st[j];
      }
      __syncthreads();   // h-tile staged (drains lgkm: st[] safe to reuse)

      // ---- gates^T = W rows @ h^T : swapped operands, full K per wave ----
      f32x4 acc0 = {0.f, 0.f, 0.f, 0.f};
      f32x4 acc1 = {0.f, 0.f, 0.f, 0.f};
#pragma unroll
      for (unsigned ks = 0; ks < 16; ks += 2) {
        unsigned c0 = ks * 4 + hi, c1 = c0 + 4;
        unsigned p0 = c0 ^ (rl & 7) ^ ((c0 >> 3) & 7);
        unsigned p1 = c1 ^ (rl & 7) ^ ((c1 >> 3) & 7);
        f16x8 h0 = *(const f16x8*)&Hl[pb][rl * 1024 + (p0 << 3)];
        f16x8 h1 = *(const f16x8*)&Hl[pb][rl * 1024 + (p1 << 3)];
        f16x8 w0 = *(const f16x8*)&Wl[rWl * 512 + ((c0 ^ (rWl & 7)) << 3)];
        f16x8 w1 = *(const f16x8*)&Wl[rWl * 512 + ((c1 ^ (rWl & 7)) << 3)];
        acc0 = __builtin_amdgcn_mfma_f32_16x16x32_f16(w0, h0, acc0, 0, 0, 0);
        acc1 = __builtin_amdgcn_mfma_f32_16x16x32_f16(w1, h1, acc1, 0, 0, 0);
      }
#pragma unroll
      for (unsigned ks = 16; ks < 32; ks += 2) {
        unsigned c0 = ks * 4 + hi, c1 = c0 + 4;
        unsigned p0 = c0 ^ (rl & 7) ^ ((c0 >> 3) & 7);
        unsigned p1 = c1 ^ (rl & 7) ^ ((c1 >> 3) & 7);
        f16x8 h0 = *(const f16x8*)&Hl[pb][rl * 1024 + (p0 << 3)];
        f16x8 h1 = *(const f16x8*)&Hl[pb][rl * 1024 + (p1 << 3)];
        acc0 = __builtin_amdgcn_mfma_f32_16x16x32_f16(breg[ks - 16], h0, acc0, 0, 0, 0);
        acc1 = __builtin_amdgcn_mfma_f32_16x16x32_f16(breg[ks - 15], h1, acc1, 0, 0, 0);
      }
      // ---- activations: lane-local i,f,g,o; 3-shuffle pack; one 8B store ----
      {
        float gi = acc0[0] + acc1[0] + (float)xv4[0];
        float gf = acc0[1] + acc1[1] + (float)xv4[1];
        float gg = acc0[2] + acc1[2] + (float)xv4[2];
        float go = acc0[3] + acc1[3] + (float)xv4[3];
        float i_ = fast_sigmoid(gi);
        float f_ = fast_sigmoid(gf);
        float g_ = fast_tanh(gg);
        float o_ = fast_sigmoid(go);
        float c_ = (s == 0) ? cA : cB;       // s compile-time (unrolled)
        c_ = f_ * c_ + i_ * g_;
        if (s == 0) cA = c_; else cB = c_;
        float hv = o_ * fast_tanh(c_);
        // pack dims nt*4+0..3 of batch sb16+rl into one 8B store by lane hi=0
        float h1v = __shfl(hv, (int)(rl + 16), 64);
        float h2v = __shfl(hv, (int)(rl + 32), 64);
        float h3v = __shfl(hv, (int)(rl + 48), 64);
        if (hi == 0) {
          union { f16 h4[4]; u64 u; } pk;
          pk.h4[0] = (f16)hv;  pk.h4[1] = (f16)h1v;
          pk.h4[2] = (f16)h2v; pk.h4[3] = (f16)h3v;
          llc_st64(h_all + ((size_t)t * B_ + sb16 + rl) * H_ + wid * 16 + nt * 4,
                   pk.u);
        }
      }
      // store drains under the next phase's spin vmcnt(0); Hl double-buffer
      // makes a second barrier unnecessary (next staging hits the other buf).
    }
  }
}

// ---------------- logits: out[b][t][c] = relu(h[t+1]) . W_score[c] ----------------

__global__ __launch_bounds__(256) void k_logits(
    const f16* __restrict__ h_all, const float* __restrict__ wsc,
    float* __restrict__ out) {
  __shared__ float Ws[2048];
  unsigned tid = threadIdx.x;
  for (unsigned i = tid; i < 512; i += 256) ((float4*)Ws)[i] = ((const float4*)wsc)[i];
  __syncthreads();
  unsigned w = tid >> 6, lane = tid & 63;
  unsigned base = blockIdx.x * 64 + w * 16;
  for (unsigned i = 0; i < 16; ++i) {
    unsigned idx = base + i;                // 0..65535
    unsigned tt = idx >> 5, b = idx & 31;
    const f16* hp = h_all + ((size_t)(idx + 32)) * H_ + lane * 16;
    f16x8 ha = *(const f16x8*)hp;
    f16x8 hb = *(const f16x8*)(hp + 8);
    float s0 = 0.f, s1 = 0.f;
#pragma unroll
    for (int z = 0; z < 8; ++z) {
      float hv = fmaxf((float)ha[z], 0.f);
      s0 += hv * Ws[lane * 16 + z];
      s1 += hv * Ws[1024 + lane * 16 + z];
    }
#pragma unroll
    for (int z = 0; z < 8; ++z) {
      float hv = fmaxf((float)hb[z], 0.f);
      s0 += hv * Ws[lane * 16 + 8 + z];
      s1 += hv * Ws[1024 + lane * 16 + 8 + z];
    }
#pragma unroll
    for (int off = 32; off; off >>= 1) {
      s0 += __shfl_xor(s0, off, 64);
      s1 += __shfl_xor(s1, off, 64);
    }
    if (lane == 0) {
      out[((size_t)b * T_ + tt) * 2 + 0] = s0;
      out[((size_t)b * T_ + tt) * 2 + 1] = s1;
    }
  }
}

// ---------------- launch ----------------

extern "C" void kernel_launch(void* const* d_in, const int* in_sizes, int n_in,
                              void* d_out, int out_size, void* d_ws, size_t ws_size,
                              hipStream_t stream) {
  const int*   seq = (const int*)d_in[0];
  const float* emb = (const float*)d_in[1];
  const float* wih = (const float*)d_in[2];
  const float* whh = (const float*)d_in[3];
  const float* bih = (const float*)d_in[4];
  const float* bhh = (const float*)d_in[5];
  const float* wsc = (const float*)d_in[6];
  float* out = (float*)d_out;
  char* ws = (char*)d_ws;

  const size_t NEED = 790874112ull;
  if (ws_size < NEED) return;  // workspace too small: output stays zero (detectable)

  f16*   emb16 = (f16*)(ws);
  f16*   wih16 = (f16*)(ws + 102926336ull);
  f16*   wr16  = (f16*)(ws + 111314944ull);
  float* bias  = (float*)(ws + 119703552ull);
  f16*   xg    = (f16*)(ws + 119719936ull);
  f16*   h_all = (f16*)(ws + 656590848ull);

  hipMemsetAsync(h_all, 0, (size_t)B_ * H_ * 2, stream);                // h_0 = 0
  hipMemsetAsync((char*)h_all + (size_t)B_ * H_ * 2, 0xFF,
                 (size_t)T_ * B_ * H_ * 2, stream);                     // poison h_1..h_T

  k_cvt_f16<<<50257, 256, 0, stream>>>(emb, emb16, 12865792L);
  k_cvt_f16<<<4096, 256, 0, stream>>>(wih, wih16, 1048576L);
  k_whh_reorder<<<2048, 256, 0, stream>>>(whh, wr16);
  k_bias<<<16, 256, 0, stream>>>(bih, bhh, bias);

  k_gemm_xg<<<16384, 256, 0, stream>>>(seq, emb16, wih16, bias, xg);
  k_lstm<<<64, 256, 0, stream>>>(xg, wr16, h_all);
  k_logits<<<1024, 256, 0, stream>>>(h_all, wsc, out);
}

// Round 19
// 11463.262 us; speedup vs baseline: 1.4660x; 1.1147x over previous
//
#include <hip/hip_runtime.h>
#include <hip/hip_bf16.h>

// LSTM classifier: emb gather -> input GEMM (fp16 MFMA) -> persistent
// recurrence with DATA-CARRIED sync (poison-tagged h words) -> logits.
// R19 = R18 + COUNTED VMCNT (T4 idiom): the wave's own h store no longer
// drains on the spin's critical path. Tail issues next-phase sweeps+xv
// BEFORE the store (store = youngest VMEM op); spin waits vmcnt(2) (sweeps
// done, store flying), pre-act vmcnt(1) (xv done), barrier = lgkmcnt(0) +
// raw s_barrier (no implicit vmcnt(0) drain). Prologue mimics steady-state
// flight with a benign zero-store to h_0.
//
// Workspace layout (bytes):
//   emb16   @ 0          : 50257*1024*2 = 102,926,336
//   wih16   @ 102926336  : 4096*1024*2  =   8,388,608
//   wr16    @ 111314944  : 4096*1024*2  =   8,388,608   (W_hh reordered, fp16)
//   bias    @ 119703552  : 4096*4       =      16,384   (b_ih + b_hh, f32)
//   xg      @ 119719936  : 65536*4096*2 = 536,870,912   (x_gates fp16, [t][b][R'])
//   h_all   @ 656590848  : 2049*32*1024*2 = 134,283,264 (h; t>=1 poisoned 0xFFFF per launch)
//   total: 790,874,112

typedef _Float16 f16;
typedef _Float16 f16x8 __attribute__((ext_vector_type(8)));
typedef _Float16 f16x4 __attribute__((ext_vector_type(4)));
typedef float    f32x4 __attribute__((ext_vector_type(4)));
typedef unsigned long long u64;

#define B_    32
#define T_    2048
#define H_    1024
#define G4_   4096

__device__ __forceinline__ void gl_lds16(const void* g, void* l) {
  __builtin_amdgcn_global_load_lds(
      (const __attribute__((address_space(1))) void*)g,
      (__attribute__((address_space(3))) void*)l, 16, 0, 0);
}

// agent-scope (LLC) 8B store — write-through past the non-coherent XCD L2s
__device__ __forceinline__ void llc_st64(void* p, u64 v) {
  __hip_atomic_store((u64*)p, v, __ATOMIC_RELAXED, __HIP_MEMORY_SCOPE_AGENT);
}

// fast activations: v_exp_f32 + v_rcp_f32 (no libm branches on critical path)
__device__ __forceinline__ float fast_sigmoid(float v) {
  return __builtin_amdgcn_rcpf(1.f + __expf(-v));
}
__device__ __forceinline__ float fast_tanh(float v) {
  return 1.f - 2.f * __builtin_amdgcn_rcpf(1.f + __expf(2.f * v));
}

// ---------------- conversions ----------------

__global__ void k_cvt_f16(const float* __restrict__ in, f16* __restrict__ out, long n4) {
  long i = (long)blockIdx.x * blockDim.x + threadIdx.x;
  if (i >= n4) return;
  float4 v = ((const float4*)in)[i];
  f16x4 o; o[0] = (f16)v.x; o[1] = (f16)v.y; o[2] = (f16)v.z; o[3] = (f16)v.w;
  *(f16x4*)(out + i * 4) = o;
}

// W_hh row (q*1024 + j) -> wr16 row R' = (j>>4)*64 + (j&15)*4 + q; fp16.
// => WG wid owns contiguous rows [wid*64, wid*64+64) = h-dims [wid*16, +16).
__global__ void k_whh_reorder(const float* __restrict__ whh, f16* __restrict__ wr) {
  unsigned i = blockIdx.x * blockDim.x + threadIdx.x;   // one thread per 8 elems
  unsigned e0 = i * 8;
  unsigned R = e0 >> 10, k = e0 & 1023;
  unsigned q = R >> 10, j = R & 1023;
  unsigned outR = ((j >> 4) << 6) + ((j & 15) << 2) + q;
  float4 v0 = ((const float4*)whh)[e0 / 4];
  float4 v1 = ((const float4*)whh)[e0 / 4 + 1];
  f16x8 o;
  o[0] = (f16)v0.x; o[1] = (f16)v0.y; o[2] = (f16)v0.z; o[3] = (f16)v0.w;
  o[4] = (f16)v1.x; o[5] = (f16)v1.y; o[6] = (f16)v1.z; o[7] = (f16)v1.w;
  *(f16x8*)&wr[((size_t)outR << 10) + k] = o;
}

__global__ void k_bias(const float* __restrict__ bi, const float* __restrict__ bh,
                       float* __restrict__ bo) {
  unsigned i = blockIdx.x * blockDim.x + threadIdx.x;
  if (i < G4_) bo[i] = bi[i] + bh[i];
}

// ---------------- input GEMM: xg[m][R'(n)] = emb[seq] @ W_ih^T + bias ----------------
// m = t*32 + b (so xg layout is [t][b][R']); 128x128 tile, BK=64, 4 waves.

__global__ __launch_bounds__(256) void k_gemm_xg(
    const int* __restrict__ seq, const f16* __restrict__ emb16,
    const f16* __restrict__ wih16, const float* __restrict__ bias,
    f16* __restrict__ xg) {
  __shared__ f16 As[128 * 64];
  __shared__ f16 Bs[128 * 64];
  const unsigned tid = threadIdx.x;
  const unsigned w = tid >> 6, lane = tid & 63;
  const unsigned bid = blockIdx.x;
  const unsigned tn = bid & 31, tm = bid >> 5;
  const unsigned wm = (w >> 1) * 64, wn = (w & 1) * 64;

  f32x4 zero = {0.f, 0.f, 0.f, 0.f};
  f32x4 acc[4][4];
#pragma unroll
  for (int i = 0; i < 4; ++i)
#pragma unroll
    for (int j = 0; j < 4; ++j) acc[i][j] = zero;

  for (unsigned kk = 0; kk < 16; ++kk) {
    const unsigned k0 = kk * 64;
#pragma unroll
    for (unsigned c = 0; c < 4; ++c) {
      unsigned idx = c * 256 + tid;
      unsigned row = idx >> 3, ch = idx & 7;
      unsigned chs = ch ^ (row & 7);
      unsigned m = tm * 128 + row;
      unsigned t = m >> 5, b = m & 31;
      int e = seq[b * 2048 + t];
      const f16* src = emb16 + ((size_t)e << 10) + k0 + chs * 8;
      gl_lds16(src, (char*)As + c * 4096 + w * 1024);
    }
#pragma unroll
    for (unsigned c = 0; c < 4; ++c) {
      unsigned idx = c * 256 + tid;
      unsigned row = idx >> 3, ch = idx & 7;
      unsigned chs = ch ^ (row & 7);
      unsigned n = tn * 128 + row;
      const f16* src = wih16 + ((size_t)n << 10) + k0 + chs * 8;
      gl_lds16(src, (char*)Bs + c * 4096 + w * 1024);
    }
    __syncthreads();
#pragma unroll
    for (unsigned ks = 0; ks < 2; ++ks) {
      f16x8 af[4], bf[4];
      unsigned kc = ks * 4 + (lane >> 4);
#pragma unroll
      for (unsigned fm = 0; fm < 4; ++fm) {
        unsigned r = wm + fm * 16 + (lane & 15);
        af[fm] = *(const f16x8*)&As[r * 64 + ((kc ^ (r & 7)) << 3)];
      }
#pragma unroll
      for (unsigned fn = 0; fn < 4; ++fn) {
        unsigned r = wn + fn * 16 + (lane & 15);
        bf[fn] = *(const f16x8*)&Bs[r * 64 + ((kc ^ (r & 7)) << 3)];
      }
#pragma unroll
      for (unsigned fm = 0; fm < 4; ++fm)
#pragma unroll
        for (unsigned fn = 0; fn < 4; ++fn)
          acc[fm][fn] = __builtin_amdgcn_mfma_f32_16x16x32_f16(af[fm], bf[fn], acc[fm][fn], 0, 0, 0);
    }
    __syncthreads();
  }
  // epilogue: + bias, fp16 store into gate-interleaved layout R'
#pragma unroll
  for (unsigned fn = 0; fn < 4; ++fn) {
    unsigned n = tn * 128 + wn + fn * 16 + (lane & 15);
    unsigned q = n >> 10, j = n & 1023;
    unsigned Rp = ((j >> 4) << 6) + ((j & 15) << 2) + q;
    float bv = bias[n];
#pragma unroll
    for (unsigned fm = 0; fm < 4; ++fm) {
#pragma unroll
      for (unsigned rg = 0; rg < 4; ++rg) {
        unsigned m = tm * 128 + wm + fm * 16 + (lane >> 4) * 4 + rg;
        xg[(size_t)m * G4_ + Rp] = (f16)(acc[fm][fn][rg] + bv);
      }
    }
  }
}

// ---------------- persistent LSTM recurrence, 2-phase, counted-vmcnt ----------------
// 64 WGs x 256 threads (4 waves = 4 M-tiles of 16 W rows, FULL K per wave:
// k<512 from Wl, k>=512 from per-wave breg). WG wid owns h-dims [wid*16,+16).
// Per-phase VMEM ledger (issue order): [sweeps(8) for NEXT phase, xv for
// NEXT phase, h store for THIS phase]. Spin: vmcnt(2) -> sweeps done, own
// store stays in flight. Pre-act: vmcnt(1) -> xv done. Retry path: vmcnt(0).
// Barrier: lgkmcnt(0) + raw s_barrier (no vmcnt drain).

__global__ __launch_bounds__(256) void k_lstm(
    const f16* __restrict__ xg, const f16* __restrict__ wr16,
    f16* __restrict__ h_all) {
  __shared__ f16 Wl[64 * 512];       // 64 KB: W_hh slice, k < 512
  __shared__ f16 Hl[2][16 * 1024];   // 64 KB: h staging, double-buffered by phase
  const unsigned tid = threadIdx.x;
  const unsigned nt = tid >> 6, lane = tid & 63;   // 4 waves = 4 M-tiles
  const unsigned wid = blockIdx.x;                 // 0..63
  const unsigned rl = lane & 15, hi = lane >> 4;

  // stage W k<512 (64 rows x 64 16B-chunks), source-swizzled, linear LDS dest
  for (unsigned c = 0; c < 16; ++c) {
    unsigned idx = c * 256 + tid;
    unsigned row = idx >> 6, ch = idx & 63;
    unsigned chs = ch ^ (row & 7);
    const f16* src = wr16 + (((size_t)wid * 64 + row) << 10) + chs * 8;
    gl_lds16(src, (char*)Wl + c * 4096 + nt * 1024);
  }

  const unsigned rWl = nt * 16 + rl;          // W row 0..63 within slice
  // breg: k in [512,1024) for this wave's own rows (asm-pinned; R3 lesson)
  f16x8 breg[16];
  {
    const f16* wp = wr16 + (((size_t)wid * 64 + rWl) << 10) + 512 + hi * 8;
#pragma unroll
    for (int j = 0; j < 16; ++j) {
      asm volatile("global_load_dwordx4 %0, %1, off\n\ts_waitcnt vmcnt(0)"
                   : "=v"(breg[j]) : "v"(wp + j * 32) : "memory");
    }
  }
  __syncthreads();   // Wl staged + breg loaded (full drain, outside the loop)

  // staging: 16 rows x 128 chunks(16B); thread owns row tid>>4, 8 chunks
  const unsigned srow = tid >> 4;            // 0..15 (batch within stream)
  const unsigned scg = (tid & 15) * 8;       // first chunk index
  float cA = 0.f, cB = 0.f;
  f16x8 st[8];
  f16x4 xvA, xvB;

  // ---- prologue: mimic steady-state VMEM flight for phase (t=1, s=0) ----
  {
    const f16* gp0 = h_all + ((size_t)srow) * H_ + scg * 8;   // h_0, batches 0-15
#pragma unroll
    for (int j = 0; j < 8; ++j)
      asm volatile("global_load_dwordx4 %0, %1, off sc0 sc1"
                   : "=v"(st[j]) : "v"(gp0 + j * 8) : "memory");
    const f16* xp = xg + ((size_t)rl) * G4_ + wid * 64 + (nt * 4 + hi) * 4;
    asm volatile("global_load_dwordx2 %0, %1, off"
                 : "=v"(xvA) : "v"(xp) : "memory");
    if (hi == 0) {  // benign zero-store: h_0 slot already holds 0
      llc_st64(h_all + ((size_t)rl) * H_ + wid * 16 + nt * 4, 0ull);
    }
  }

  for (unsigned t = 1; t <= (unsigned)T_; ++t) {
#pragma unroll
    for (int s = 0; s < 2; ++s) {
      const unsigned sb16 = s * 16;
      const unsigned pb = ((t - 1) * 2 + s) & 1;   // Hl phase buffer
      const f16* gp = h_all + ((size_t)(t - 1) * B_ + sb16 + srow) * H_ + scg * 8;
      // ---- spin: counted wait (sweeps done; own store keeps flying) ----
      asm volatile("s_waitcnt vmcnt(2)" ::: "memory");
      __builtin_amdgcn_sched_barrier(0);   // rule #18
      while (true) {
        bool ok = true;
#pragma unroll
        for (int j = 0; j < 8; ++j) {
          union { f16x8 v; u64 u[2]; } uu; uu.v = st[j];
          ok = ok && (uu.u[0] != ~0ull) && (uu.u[1] != ~0ull);
        }
        if (ok) break;
        __builtin_amdgcn_s_sleep(1);
#pragma unroll
        for (int j = 0; j < 8; ++j)
          asm volatile("global_load_dwordx4 %0, %1, off sc0 sc1"
                       : "=v"(st[j]) : "v"(gp + j * 8) : "memory");
        asm volatile("s_waitcnt vmcnt(0)" ::: "memory");
        __builtin_amdgcn_sched_barrier(0);
      }
      // ---- stage into dual-XOR swizzled Hl[pb] ----
#pragma unroll
      for (int j = 0; j < 8; ++j) {
        unsigned cc = scg + j;
        unsigned pos = cc ^ (srow & 7) ^ ((cc >> 3) & 7);   // dual-XOR swizzle
        *(f16x8*)&Hl[pb][srow * 1024 + (pos << 3)] = st[j];
      }
      // barrier WITHOUT vmcnt drain: LDS-drain + raw s_barrier
      asm volatile("s_waitcnt lgkmcnt(0)" ::: "memory");
      __builtin_amdgcn_sched_barrier(0);
      __builtin_amdgcn_s_barrier();

      // ---- gates^T = W rows @ h^T : swapped operands, full K per wave ----
      f32x4 acc0 = {0.f, 0.f, 0.f, 0.f};
      f32x4 acc1 = {0.f, 0.f, 0.f, 0.f};
#pragma unroll
      for (unsigned ks = 0; ks < 16; ks += 2) {
        unsigned c0 = ks * 4 + hi, c1 = c0 + 4;
        unsigned p0 = c0 ^ (rl & 7) ^ ((c0 >> 3) & 7);
        unsigned p1 = c1 ^ (rl & 7) ^ ((c1 >> 3) & 7);
        f16x8 h0 = *(const f16x8*)&Hl[pb][rl * 1024 + (p0 << 3)];
        f16x8 h1 = *(const f16x8*)&Hl[pb][rl * 1024 + (p1 << 3)];
        f16x8 w0 = *(const f16x8*)&Wl[rWl * 512 + ((c0 ^ (rWl & 7)) << 3)];
        f16x8 w1 = *(const f16x8*)&Wl[rWl * 512 + ((c1 ^ (rWl & 7)) << 3)];
        acc0 = __builtin_amdgcn_mfma_f32_16x16x32_f16(w0, h0, acc0, 0, 0, 0);
        acc1 = __builtin_amdgcn_mfma_f32_16x16x32_f16(w1, h1, acc1, 0, 0, 0);
      }
#pragma unroll
      for (unsigned ks = 16; ks < 32; ks += 2) {
        unsigned c0 = ks * 4 + hi, c1 = c0 + 4;
        unsigned p0 = c0 ^ (rl & 7) ^ ((c0 >> 3) & 7);
        unsigned p1 = c1 ^ (rl & 7) ^ ((c1 >> 3) & 7);
        f16x8 h0 = *(const f16x8*)&Hl[pb][rl * 1024 + (p0 << 3)];
        f16x8 h1 = *(const f16x8*)&Hl[pb][rl * 1024 + (p1 << 3)];
        acc0 = __builtin_amdgcn_mfma_f32_16x16x32_f16(breg[ks - 16], h0, acc0, 0, 0, 0);
        acc1 = __builtin_amdgcn_mfma_f32_16x16x32_f16(breg[ks - 15], h1, acc1, 0, 0, 0);
      }
      // ---- pre-act: drain xv (own store may still fly) ----
      asm volatile("s_waitcnt vmcnt(1)" ::: "memory");
      __builtin_amdgcn_sched_barrier(0);
      f16x4 xv4 = (s == 0) ? xvA : xvB;    // s compile-time (unrolled)

      // ---- issue NEXT phase sweeps + xv (oldest), store comes last ----
      unsigned nt_t = (s == 0) ? t : (t < (unsigned)T_ ? t + 1 : t);
      unsigned nsb = (s == 0) ? 16u : 0u;
      const f16* gpn = h_all + ((size_t)(nt_t - 1) * B_ + nsb + srow) * H_ + scg * 8;
#pragma unroll
      for (int j = 0; j < 8; ++j)
        asm volatile("global_load_dwordx4 %0, %1, off sc0 sc1"
                     : "=v"(st[j]) : "v"(gpn + j * 8) : "memory");
      {
        const f16* xpn = xg + ((size_t)(nt_t - 1) * B_ + nsb + rl) * G4_
                         + wid * 64 + (nt * 4 + hi) * 4;
        if (s == 0)
          asm volatile("global_load_dwordx2 %0, %1, off"
                       : "=v"(xvB) : "v"(xpn) : "memory");
        else
          asm volatile("global_load_dwordx2 %0, %1, off"
                       : "=v"(xvA) : "v"(xpn) : "memory");
      }

      // ---- activations: lane-local i,f,g,o; 3-shuffle pack; 8B store LAST ----
      {
        float gi = acc0[0] + acc1[0] + (float)xv4[0];
        float gf = acc0[1] + acc1[1] + (float)xv4[1];
        float gg = acc0[2] + acc1[2] + (float)xv4[2];
        float go = acc0[3] + acc1[3] + (float)xv4[3];
        float i_ = fast_sigmoid(gi);
        float f_ = fast_sigmoid(gf);
        float g_ = fast_tanh(gg);
        float o_ = fast_sigmoid(go);
        float c_ = (s == 0) ? cA : cB;
        c_ = f_ * c_ + i_ * g_;
        if (s == 0) cA = c_; else cB = c_;
        float hv = o_ * fast_tanh(c_);
        float h1v = __shfl(hv, (int)(rl + 16), 64);
        float h2v = __shfl(hv, (int)(rl + 32), 64);
        float h3v = __shfl(hv, (int)(rl + 48), 64);
        if (hi == 0) {
          union { f16 h4[4]; u64 u; } pk;
          pk.h4[0] = (f16)hv;  pk.h4[1] = (f16)h1v;
          pk.h4[2] = (f16)h2v; pk.h4[3] = (f16)h3v;
          llc_st64(h_all + ((size_t)t * B_ + sb16 + rl) * H_ + wid * 16 + nt * 4,
                   pk.u);
        }
      }
      // store is youngest VMEM op; next spin's vmcnt(2) leaves it flying.
    }
  }
}

// ---------------- logits: out[b][t][c] = relu(h[t+1]) . W_score[c] ----------------

__global__ __launch_bounds__(256) void k_logits(
    const f16* __restrict__ h_all, const float* __restrict__ wsc,
    float* __restrict__ out) {
  __shared__ float Ws[2048];
  unsigned tid = threadIdx.x;
  for (unsigned i = tid; i < 512; i += 256) ((float4*)Ws)[i] = ((const float4*)wsc)[i];
  __syncthreads();
  unsigned w = tid >> 6, lane = tid & 63;
  unsigned base = blockIdx.x * 64 + w * 16;
  for (unsigned i = 0; i < 16; ++i) {
    unsigned idx = base + i;                // 0..65535
    unsigned tt = idx >> 5, b = idx & 31;
    const f16* hp = h_all + ((size_t)(idx + 32)) * H_ + lane * 16;
    f16x8 ha = *(const f16x8*)hp;
    f16x8 hb = *(const f16x8*)(hp + 8);
    float s0 = 0.f, s1 = 0.f;
#pragma unroll
    for (int z = 0; z < 8; ++z) {
      float hv = fmaxf((float)ha[z], 0.f);
      s0 += hv * Ws[lane * 16 + z];
      s1 += hv * Ws[1024 + lane * 16 + z];
    }
#pragma unroll
    for (int z = 0; z < 8; ++z) {
      float hv = fmaxf((float)hb[z], 0.f);
      s0 += hv * Ws[lane * 16 + 8 + z];
      s1 += hv * Ws[1024 + lane * 16 + 8 + z];
    }
#pragma unroll
    for (int off = 32; off; off >>= 1) {
      s0 += __shfl_xor(s0, off, 64);
      s1 += __shfl_xor(s1, off, 64);
    }
    if (lane == 0) {
      out[((size_t)b * T_ + tt) * 2 + 0] = s0;
      out[((size_t)b * T_ + tt) * 2 + 1] = s1;
    }
  }
}

// ---------------- launch ----------------

extern "C" void kernel_launch(void* const* d_in, const int* in_sizes, int n_in,
                              void* d_out, int out_size, void* d_ws, size_t ws_size,
                              hipStream_t stream) {
  const int*   seq = (const int*)d_in[0];
  const float* emb = (const float*)d_in[1];
  const float* wih = (const float*)d_in[2];
  const float* whh = (const float*)d_in[3];
  const float* bih = (const float*)d_in[4];
  const float* bhh = (const float*)d_in[5];
  const float* wsc = (const float*)d_in[6];
  float* out = (float*)d_out;
  char* ws = (char*)d_ws;

  const size_t NEED = 790874112ull;
  if (ws_size < NEED) return;  // workspace too small: output stays zero (detectable)

  f16*   emb16 = (f16*)(ws);
  f16*   wih16 = (f16*)(ws + 102926336ull);
  f16*   wr16  = (f16*)(ws + 111314944ull);
  float* bias  = (float*)(ws + 119703552ull);
  f16*   xg    = (f16*)(ws + 119719936ull);
  f16*   h_all = (f16*)(ws + 656590848ull);

  hipMemsetAsync(h_all, 0, (size_t)B_ * H_ * 2, stream);                // h_0 = 0
  hipMemsetAsync((char*)h_all + (size_t)B_ * H_ * 2, 0xFF,
                 (size_t)T_ * B_ * H_ * 2, stream);                     // poison h_1..h_T

  k_cvt_f16<<<50257, 256, 0, stream>>>(emb, emb16, 12865792L);
  k_cvt_f16<<<4096, 256, 0, stream>>>(wih, wih16, 1048576L);
  k_whh_reorder<<<2048, 256, 0, stream>>>(whh, wr16);
  k_bias<<<16, 256, 0, stream>>>(bih, bhh, bias);

  k_gemm_xg<<<16384, 256, 0, stream>>>(seq, emb16, wih16, bias, xg);
  k_lstm<<<64, 256, 0, stream>>>(xg, wr16, h_all);
  k_logits<<<1024, 256, 0, stream>>>(h_all, wsc, out);
}